// Round 7
// baseline (1184.107 us; speedup 1.0000x reference)
//
#include <hip/hip_runtime.h>
#include <math.h>

// BWNet scan v7: same-L2 exchange.
// Scan role on bid%8==0 of a 256-block grid -> all 32 scan blocks on ONE XCD
// (mapping evidence: v4's FETCH drop under the same trick). Exchange words go
// through sc0 global ops (bypass L1, hit the SHARED XCD L2, ~200cy) instead of
// agent-scope sc1 (MALL round trip). Safety:
//  - startup hello round (sc0) + verdict consensus (agent-scope, always
//    coherent): if any block missed a hello, ALL blocks fall back to the
//    proven agent-scope exchange.
//  - per-iteration tag salt: k_init atomically bumps a stamp; tags are
//    stamp*70+step, so stale residue never aliases a live tag (no zeroing
//    needed, immune to rocprof replays / warmups).
// k_init (256 blocks): keys GEMM + func_embed + output zero + stamp bump.

typedef float v4f __attribute__((ext_vector_type(4)));
typedef unsigned long long ull;

#define N_ENT 8192
#define EMB   256
#define KD    32
#define ARD   1024
#define UT    233
#define NSCAN 32

// workspace float-index offsets
#define WS_KEYS 0         // 32*8192 floats, k-major: keys[k*8192+j]
#define WS_C0   262144    // 256: b_a0 + relu(W_fe@um + b_fe)
#define WS_PAIR 262400    // tagged-pair region (byte 1049600, 8B aligned)
#define PR_RI0  0         // 256 pairs: ri0[j], written by scan block j>>3
#define PR_PART 256       // 32 blocks * 40 pairs: [0]=psum [1]=pmax [2]=pidx [3..34]=cand
#define PR_HELLO 1536     // 32 blocks * stride 8 (own 64B line each)
#define PR_VERD  1792     // 32 verdict pairs
#define PR_STAMP 1824     // 1 pair: per-iteration stamp counter

struct Params {
  const float *um, *emask, *enc, *arin, *W_fe, *b_fe, *W_k, *b_k,
              *W_a0, *b_a0, *W_a1, *b_a1, *W_f, *b_f, *W_i0, *b_i0,
              *W_i1, *b_i1, *W_o, *b_o, *ln_g, *ln_b, *W_a3, *b_a3;
  const int* ct;
  float* out;
  float* wsf;
  int*   wsi;
};

__device__ __forceinline__ ull ld_pair(ull* p_) {
  return __hip_atomic_load(p_, __ATOMIC_RELAXED, __HIP_MEMORY_SCOPE_AGENT);
}
__device__ __forceinline__ void st_pair(ull* p_, ull v) {
  __hip_atomic_store(p_, v, __ATOMIC_RELAXED, __HIP_MEMORY_SCOPE_AGENT);
}
// sc0 ops: bypass L1, served by the XCD's L2 (valid only when all scan blocks
// share an XCD -- guarded by the hello/verdict consensus).
__device__ __forceinline__ ull ld_l2(ull* p_) {
  ull r;
  asm volatile("global_load_dwordx2 %0, %1, off sc0\n\ts_waitcnt vmcnt(0)"
               : "=&v"(r) : "v"(p_) : "memory");
  return r;
}
__device__ __forceinline__ void st_l2(ull* p_, ull v) {
  asm volatile("global_store_dwordx2 %0, %1, off sc0" :: "v"(p_), "v"(v) : "memory");
}
__device__ __forceinline__ ull ld_ex(ull* p_, bool fast) {
  return fast ? ld_l2(p_) : ld_pair(p_);
}
__device__ __forceinline__ void st_ex(ull* p_, ull v, bool fast) {
  if (fast) st_l2(p_, v); else st_pair(p_, v);
}
__device__ __forceinline__ ull packf(float v, unsigned tag) {
  return ((ull)tag << 32) | (ull)__float_as_uint(v);
}
__device__ __forceinline__ ull packi(int v, unsigned tag) {
  return ((ull)tag << 32) | (ull)(unsigned)v;
}
__device__ __forceinline__ unsigned ptag(ull u) { return (unsigned)(u >> 32); }
__device__ __forceinline__ float pvalf(ull u) { return __uint_as_float((unsigned)u); }

// LDS-only barrier: drains lgkmcnt but NOT vmcnt (global stores keep flying).
__device__ __forceinline__ void bar_lds() {
  asm volatile("s_waitcnt lgkmcnt(0)\n\ts_barrier" ::: "memory");
}

// ---------------- init: keys GEMM, func_embed, output zero, stamp bump ----------------
__global__ __launch_bounds__(256) void k_init(Params p) {
  __shared__ float enc_s[32 * 260];
  __shared__ float um_s[UT];
  const int tid = threadIdx.x, bid = blockIdx.x;
  float* keys = p.wsf + WS_KEYS;
  const size_t NN = (size_t)N_ENT * N_ENT;

  if (bid == 0 && tid < UT) um_s[tid] = p.um[tid];
  if (bid == 3 && tid == 0) {  // per-iteration stamp (tag salt)
    ull* st = (ull*)(p.wsf + WS_PAIR) + PR_STAMP;
    __hip_atomic_fetch_add(st, 1ull, __ATOMIC_RELAXED, __HIP_MEMORY_SCOPE_AGENT);
  }

  const int j0 = bid * 32;
  #pragma unroll
  for (int i = 0; i < 8; ++i) {
    int idx = i * 256 + tid;
    int row = idx >> 6, c4 = idx & 63;
    v4f v = *(const v4f*)(p.enc + (size_t)(j0 + row) * EMB + c4 * 4);
    *(v4f*)&enc_s[row * 260 + c4 * 4] = v;
  }
  __syncthreads();
  {
    const int jl = tid >> 3, kg = tid & 7;
    float acc[4];
    #pragma unroll
    for (int kk = 0; kk < 4; ++kk) acc[kk] = p.b_k[kg * 4 + kk];
    for (int e4 = 0; e4 < 64; ++e4) {
      v4f x = *(const v4f*)&enc_s[jl * 260 + e4 * 4];
      #pragma unroll
      for (int kk = 0; kk < 4; ++kk) {
        v4f w = *(const v4f*)(p.W_k + (size_t)(kg * 4 + kk) * EMB + e4 * 4);
        acc[kk] += x.x * w.x + x.y * w.y + x.z * w.z + x.w * w.w;
      }
    }
    const int j = j0 + jl;
    #pragma unroll
    for (int kk = 0; kk < 4; ++kk) keys[(size_t)(kg * 4 + kk) * N_ENT + j] = acc[kk];
  }
  if (bid == 0) {
    float a = p.b_fe[tid];
    const float* wr = p.W_fe + (size_t)tid * UT;
    for (int u = 0; u < UT; ++u) a += wr[u] * um_s[u];
    p.wsf[WS_C0 + tid] = fmaxf(a, 0.f) + p.b_a0[tid];
  }

  // zero the whole unit_logits region at full 256-block HBM bandwidth
  {
    v4f z = (v4f){0.f, 0.f, 0.f, 0.f};
    v4f* o4 = (v4f*)p.out;
    const size_t tot = NN / 4;
    for (size_t i = (size_t)bid * 256 + tid; i < tot; i += (size_t)256 * 256)
      __builtin_nontemporal_store(z, o4 + i);
  }
}

// ---------------- main: scan on bid%8==0 (one XCD), sc0-L2 exchange ----------------
__global__ __launch_bounds__(256, 1) void k_scan(Params p) {
  const int tid = threadIdx.x, bid = blockIdx.x;
  if ((bid & 7) != 0) return;          // only one block per XCD-slot 0 survives
  const int sid = bid >> 3;            // 0..31, all on one XCD if %8 maps XCD
  int ctv = p.ct[0];
  const int steps = ctv < 0 ? 0 : (ctv > 64 ? 64 : ctv);
  const size_t NN = (size_t)N_ENT * N_ENT;

  __shared__ float w1_lds[32 * 257];
  __shared__ float wg_lds[128 * 65];
  __shared__ float ar_s[32 * 33];
  __shared__ float ri0f[256];
  __shared__ float xcat[64];           // [0..32)=i1, [32..64)=q
  __shared__ float h_s[32], qnf[32], cent[32];
  __shared__ unsigned maskb[256], selb[256];
  __shared__ float b_a1s[32], gb_s[128], lng_s[32], lnb_s[32], c0own[8];
  __shared__ float reds[4], rmaxs[4];
  __shared__ int   ridxs[4];
  __shared__ float ssum_s;
  __shared__ int   upd_s, done_s, fast_s;

  ull* pairb = (ull*)(p.wsf + WS_PAIR);
  ull* ri0p  = pairb + PR_RI0;
  ull* partp = pairb + PR_PART;
  ull* hellop = pairb + PR_HELLO;
  ull* verdp  = pairb + PR_VERD;
  const float* keys = p.wsf + WS_KEYS;

  const unsigned stamp = (unsigned)ld_pair(pairb + PR_STAMP);
  const unsigned base = stamp * 70u;   // tags base+1..base+65 steps, +68 hello, +69 verdict

  // ---- preamble: replicated state + weights into LDS / registers ----
  for (int i = tid; i < ARD; i += 256) ar_s[(i >> 5) * 33 + (i & 31)] = p.arin[i];
  {
    unsigned mb = 0u;
    const float* em = p.emask + (size_t)tid * 32;
    #pragma unroll
    for (int j = 0; j < 32; ++j) mb |= (em[j] != 0.f) ? (1u << j) : 0u;
    maskb[tid] = mb; selb[tid] = 0u;
  }
  for (int idx = tid; idx < 32 * 256; idx += 256) {
    const int r = idx >> 8, c = idx & 255;
    w1_lds[r * 257 + c] = p.W_a1[idx];
  }
  for (int idx = tid; idx < 128 * 64; idx += 256) {
    const int row = idx >> 6, c = idx & 63;
    const float* W = (row < 32) ? p.W_f : (row < 64) ? p.W_i0 : (row < 96) ? p.W_i1 : p.W_o;
    wg_lds[row * 65 + c] = W[(row & 31) * 64 + c];
  }
  if (tid < 32) {
    b_a1s[tid] = p.b_a1[tid];
    lng_s[tid] = p.ln_g[tid]; lnb_s[tid] = p.ln_b[tid];
    h_s[tid] = 0.f; qnf[tid] = 0.f; xcat[32 + tid] = 0.f; xcat[tid] = 0.f;
  }
  if (tid < 128) {
    const int g = tid >> 5, r = tid & 31;
    const float* bg = (g == 0) ? p.b_f : (g == 1) ? p.b_i0 : (g == 2) ? p.b_i1 : p.b_o;
    gb_s[tid] = bg[r];
  }
  if (tid < 8) c0own[tid] = p.wsf[WS_C0 + sid * 8 + tid];
  if (tid == 0) done_s = 0;

  v4f w0[8];  // W_a0 rows [8*sid,8*sid+8)
  { const float* s = p.W_a0 + (size_t)(sid * 8 + (tid >> 5)) * ARD + (tid & 31) * 32;
    #pragma unroll
    for (int i = 0; i < 8; ++i) w0[i] = ((const v4f*)s)[i]; }
  v4f w3[32]; // W_a3 rows {tid, tid+256, tid+512, tid+768}
  float b3[4];
  #pragma unroll
  for (int rr = 0; rr < 4; ++rr) {
    const float* s = p.W_a3 + (size_t)(tid + 256 * rr) * KD;
    #pragma unroll
    for (int i = 0; i < 8; ++i) w3[rr * 8 + i] = ((const v4f*)s)[i];
    b3[rr] = p.b_a3[tid + 256 * rr];
  }
  float kc[32];  // this thread's key column
  { const int gcol = sid * 256 + tid;
    #pragma unroll
    for (int k = 0; k < 32; ++k) kc[k] = keys[(size_t)k * N_ENT + gcol]; }
  __syncthreads();

  // ---- hello (sc0) + verdict consensus (agent) -> fast mode decision ----
  {
    int okv = 1;
    if (tid == 0) st_l2(&hellop[sid * 8], packi(sid, base + 68u));
    if (tid < 32) {
      int seen = 0, it = 0;
      for (;;) {
        if (!seen) { ull u = ld_l2(&hellop[tid * 8]); if (ptag(u) == base + 68u) seen = 1; }
        unsigned long long bal = __ballot(seen != 0);
        if ((bal & 0xFFFFFFFFull) == 0xFFFFFFFFull) break;
        if (++it > 64) { okv = 0; break; }
      }
    }
    if (tid == 0) st_pair(&verdp[sid], packi(okv, base + 69u));
    if (tid < 32) {
      ull u; int guard = 0;
      for (;;) {
        u = ld_pair(&verdp[tid]);
        if (ptag(u) == base + 69u) break;
        if (++guard > (1 << 20)) break;
        __builtin_amdgcn_s_sleep(1);
      }
      const int ok = (ptag(u) == base + 69u) && (((int)(unsigned)u) != 0);
      unsigned long long bal = __ballot(ok);
      if (tid == 0) fast_s = ((bal & 0xFFFFFFFFull) == 0xFFFFFFFFull) ? 1 : 0;
    }
    bar_lds();
  }
  const bool fast = (fast_s != 0);
  const int guard_max = fast ? (1 << 17) : (1 << 20);

  auto produce = [&](unsigned tag) {
    const int seg = tid & 31, rl = tid >> 5;
    const float* a = &ar_s[seg * 33];
    float pa = 0.f;
    #pragma unroll
    for (int i = 0; i < 8; ++i) {
      v4f av = *(const v4f*)(a + 4 * i);
      pa += w0[i].x * av.x + w0[i].y * av.y + w0[i].z * av.z + w0[i].w * av.w;
    }
    #pragma unroll
    for (int m = 16; m; m >>= 1) pa += __shfl_xor(pa, m);
    if (seg == 0)
      st_ex(&ri0p[sid * 8 + rl], packf(fmaxf(pa + c0own[rl], 0.f), tag), fast);
  };
  produce(base + 1u);  // ri0 for step 0

  float v_reg = 0.f;
  for (int t = 0; t < steps; ++t) {
    const unsigned tg = base + 1u + (unsigned)t;

    // ==== Phase A1: wave0 polls ri0 (4 tags/lane), stages to LDS ====
    if (tid < 64) {
      ull u0, u1, u2, u3; int guard = 0;
      for (;;) {
        u0 = ld_ex(&ri0p[tid], fast);
        u1 = ld_ex(&ri0p[tid + 64], fast);
        u2 = ld_ex(&ri0p[tid + 128], fast);
        u3 = ld_ex(&ri0p[tid + 192], fast);
        if ((ptag(u0) == tg) && (ptag(u1) == tg) && (ptag(u2) == tg) && (ptag(u3) == tg)) break;
        if (++guard > guard_max) break;  // failsafe: never hang
        if (!fast) __builtin_amdgcn_s_sleep(1);
      }
      ri0f[tid] = pvalf(u0); ri0f[tid + 64] = pvalf(u1);
      ri0f[tid + 128] = pvalf(u2); ri0f[tid + 192] = pvalf(u3);
    }
    bar_lds();
    const int act = (done_s == 0);

    // ==== Phase A2: wave0 solo LSTM chain ====
    if (tid < 64) {
      {
        const int r = tid & 31, h = tid >> 5;
        const float* wrow = &w1_lds[r * 257 + h * 128];
        const float* xrow = &ri0f[h * 128];
        float p1 = 0.f;
        #pragma unroll
        for (int i = 0; i < 32; ++i) {
          v4f wv = *(const v4f*)(wrow + 4 * i);
          v4f xv = *(const v4f*)(xrow + 4 * i);
          p1 += wv.x * xv.x + wv.y * xv.y + wv.z * xv.z + wv.w * xv.w;
        }
        p1 += __shfl_xor(p1, 32);
        if (h == 0) xcat[r] = fmaxf(p1 + b_a1s[r], 0.f);
      }
      float ga, gb;
      {
        float pg0 = 0.f, pg1 = 0.f;
        #pragma unroll
        for (int i = 0; i < 16; ++i) {
          v4f xv = *(const v4f*)&xcat[4 * i];
          v4f wa = *(const v4f*)&wg_lds[tid * 65 + 4 * i];
          v4f wb = *(const v4f*)&wg_lds[(tid + 64) * 65 + 4 * i];
          pg0 += wa.x * xv.x + wa.y * xv.y + wa.z * xv.z + wa.w * xv.w;
          pg1 += wb.x * xv.x + wb.y * xv.y + wb.z * xv.z + wb.w * xv.w;
        }
        pg0 += gb_s[tid]; pg1 += gb_s[tid + 64];
        ga = 1.f / (1.f + __expf(-pg0));
        gb = (tid < 32) ? tanhf(pg1) : 1.f / (1.f + __expf(-pg1));
      }
      const float gbx = __shfl_xor(gb, 32);
      float y;
      {
        const int k = tid & 31;
        const float a = (tid < 32) ? ga : ga * gbx;
        float s = a;
        #pragma unroll
        for (int m = 16; m; m >>= 1) s += __shfl_xor(s, m);
        const float mean = s * (1.f / 32.f);
        const float d = a - mean;
        float vv = d * d;
        #pragma unroll
        for (int m = 16; m; m >>= 1) vv += __shfl_xor(vv, m);
        vv *= (1.f / 32.f);
        y = d * rsqrtf(vv + 1e-5f) * lng_s[k] + lnb_s[k];
      }
      const float remv = __shfl_xor(y, 32);
      if (tid < 32) {
        const float a = gbx;  // sig(o)
        float s = a;
        #pragma unroll
        for (int m = 16; m; m >>= 1) s += __shfl_xor(s, m);
        const float mean = s * (1.f / 32.f);
        const float d = a - mean;
        float vv = d * d;
        #pragma unroll
        for (int m = 16; m; m >>= 1) vv += __shfl_xor(vv, m);
        vv *= (1.f / 32.f);
        const float yo = d * rsqrtf(vv + 1e-5f) * lng_s[tid] + lnb_s[tid];
        const float nh = remv + y * h_s[tid];
        const float qv = tanhf(nh) * yo;
        qnf[tid] = qv;
        if (act) { h_s[tid] = nh; xcat[32 + tid] = qv; }
      }
    }
    bar_lds();

    // ==== Phase A3: sweep (all threads) ====
    {
      float dot = 0.f;
      #pragma unroll
      for (int k = 0; k < 32; ++k) dot += qnf[k] * kc[k];
      const float sig = 1.f / (1.f + __expf(-dot));
      const float v = __expf(__logf(sig) / 0.8f);  // sig^(1/TEMP)
      v_reg = v;
      float sv = v, mv = v;
      int mi = (sid << 8) + tid;
      #pragma unroll
      for (int m = 32; m; m >>= 1) {
        sv += __shfl_xor(sv, m);
        const float ov = __shfl_xor(mv, m);
        const int oi = __shfl_xor(mi, m);
        if (ov > mv || (ov == mv && oi < mi)) { mv = ov; mi = oi; }
      }
      const int wv = tid >> 6;
      if ((tid & 63) == 0) { reds[wv] = sv; rmaxs[wv] = mv; ridxs[wv] = mi; }
    }
    bar_lds();
    {  // block reduce; record + column ship issue together
      const float Sb = ((reds[0] + reds[1]) + reds[2]) + reds[3];
      float Mb = rmaxs[0]; int Ib = ridxs[0];
      #pragma unroll
      for (int i2 = 1; i2 < 4; ++i2)
        if (rmaxs[i2] > Mb || (rmaxs[i2] == Mb && ridxs[i2] < Ib)) { Mb = rmaxs[i2]; Ib = ridxs[i2]; }
      ull* rec = &partp[sid * 40];
      if (tid == 0) {
        st_ex(&rec[0], packf(Sb, tg), fast);
        st_ex(&rec[1], packf(Mb, tg), fast);
        st_ex(&rec[2], packi(Ib, tg), fast);
      }
      if (((sid << 8) | tid) == Ib) {
        #pragma unroll
        for (int k = 0; k < 32; ++k) st_ex(&rec[3 + k], packf(kc[k], tg), fast);
      }
    }

    // ==== Phase B: lanes 0-31 poll records -> reduce -> cand poll ====
    if (tid < 32) {
      ull* rec = &partp[tid * 40];
      ull u0, u1, u2; int guard = 0;
      for (;;) {
        u0 = ld_ex(&rec[0], fast); u1 = ld_ex(&rec[1], fast); u2 = ld_ex(&rec[2], fast);
        if ((ptag(u0) == tg) && (ptag(u1) == tg) && (ptag(u2) == tg)) break;
        if (++guard > guard_max) break;
        if (!fast) __builtin_amdgcn_s_sleep(1);
      }
      float s = pvalf(u0), m = pvalf(u1);
      int ii = (int)(unsigned)u2;
      #pragma unroll
      for (int mm = 16; mm; mm >>= 1) {
        s += __shfl_xor(s, mm);
        const float om = __shfl_xor(m, mm);
        const int oi = __shfl_xor(ii, mm);
        if (om > m || (om == m && oi < ii)) { m = om; ii = oi; }
      }
      ull* crec = &partp[(ii >> 8) * 40 + 3];
      ull uc; guard = 0;
      for (;;) {
        uc = ld_ex(&crec[tid], fast);
        if (ptag(uc) == tg) break;
        if (++guard > guard_max) break;
        if (!fast) __builtin_amdgcn_s_sleep(1);
      }
      const float kv = pvalf(uc);
      float mn = kv;
      #pragma unroll
      for (int mm = 16; mm; mm >>= 1) mn += __shfl_xor(mn, mm);
      mn *= (1.f / 32.f);
      const float cv = kv - mn;
      cent[tid] = cv;
      const unsigned long long bb = __ballot(cv != cv);
      if (tid == 0) {
        const int valid = (s != 0.f);
        const int nf = (bb == 0) ? 1 : 0;
        const unsigned mw = maskb[ii >> 5];
        const int hit = (act && valid && ((mw >> (ii & 31)) & 1)) ? 1 : 0;
        ssum_s = s;
        upd_s = (hit && nf) ? 1 : 0;
        if (hit) {
          maskb[ii >> 5] = mw & ~(1u << (ii & 31));
          selb[ii >> 5] |= (1u << (ii & 31));
          if (!nf) done_s = 1;
        }
      }
    }
    bar_lds();
    {  // row write for step t
      const float S = ssum_s;
      const float rowv = (act && (S != 0.f)) ? (v_reg / S) : 0.f;
      __builtin_nontemporal_store(rowv, p.out + (size_t)t * N_ENT + (sid << 8) + tid);
    }
    if (upd_s) {  // replicated ar update: 4 rows/thread, W_a3 in registers
      float cc[32];
      #pragma unroll
      for (int g = 0; g < 8; ++g) {
        v4f x = *(const v4f*)&cent[4 * g];
        cc[4 * g] = x.x; cc[4 * g + 1] = x.y; cc[4 * g + 2] = x.z; cc[4 * g + 3] = x.w;
      }
      float dl0 = b3[0], dl1 = b3[1], dl2 = b3[2], dl3 = b3[3];
      #pragma unroll
      for (int c = 0; c < 32; ++c) {
        const float cv = cc[c];
        dl0 += w3[c >> 2][c & 3] * cv;
        dl1 += w3[8 + (c >> 2)][c & 3] * cv;
        dl2 += w3[16 + (c >> 2)][c & 3] * cv;
        dl3 += w3[24 + (c >> 2)][c & 3] * cv;
      }
      if (dl0 > 0.f) ar_s[(tid >> 5) * 33 + (tid & 31)] += dl0;
      const int r1 = tid + 256, r2 = tid + 512, r3 = tid + 768;
      if (dl1 > 0.f) ar_s[(r1 >> 5) * 33 + (r1 & 31)] += dl1;
      if (dl2 > 0.f) ar_s[(r2 >> 5) * 33 + (r2 & 31)] += dl2;
      if (dl3 > 0.f) ar_s[(r3 >> 5) * 33 + (r3 & 31)] += dl3;
    }
    bar_lds();
    produce(tg + 1u);  // ri0 for step t+1
  }
  __syncthreads();

  // ==== epilogue: sel_out and ar_out (replicated state) ====
  if (sid == 0) {
    for (int i = tid; i < N_ENT; i += 256)
      p.out[NN + i] = ((selb[i >> 5] >> (i & 31)) & 1u) ? 1.f : 0.f;
  } else if (sid == 1) {
    for (int i = tid; i < ARD; i += 256)
      p.out[NN + N_ENT + i] = ar_s[(i >> 5) * 33 + (i & 31)];
  }
}

extern "C" void kernel_launch(void* const* d_in, const int* in_sizes, int n_in,
                              void* d_out, int out_size, void* d_ws, size_t ws_size,
                              hipStream_t stream) {
  (void)in_sizes; (void)n_in; (void)out_size; (void)ws_size;
  Params p;
  p.um    = (const float*)d_in[0];
  p.emask = (const float*)d_in[1];
  p.enc   = (const float*)d_in[2];
  p.arin  = (const float*)d_in[3];
  p.W_fe  = (const float*)d_in[4];
  p.b_fe  = (const float*)d_in[5];
  p.W_k   = (const float*)d_in[6];
  p.b_k   = (const float*)d_in[7];
  p.W_a0  = (const float*)d_in[8];
  p.b_a0  = (const float*)d_in[9];
  p.W_a1  = (const float*)d_in[10];
  p.b_a1  = (const float*)d_in[11];
  p.W_f   = (const float*)d_in[12];
  p.b_f   = (const float*)d_in[13];
  p.W_i0  = (const float*)d_in[14];
  p.b_i0  = (const float*)d_in[15];
  p.W_i1  = (const float*)d_in[16];
  p.b_i1  = (const float*)d_in[17];
  p.W_o   = (const float*)d_in[18];
  p.b_o   = (const float*)d_in[19];
  p.ln_g  = (const float*)d_in[20];
  p.ln_b  = (const float*)d_in[21];
  p.W_a3  = (const float*)d_in[22];
  p.b_a3  = (const float*)d_in[23];
  p.ct    = (const int*)d_in[24];
  p.out   = (float*)d_out;
  p.wsf   = (float*)d_ws;
  p.wsi   = (int*)d_ws;

  hipLaunchKernelGGL(k_init, dim3(256), dim3(256), 0, stream, p);
  hipLaunchKernelGGL(k_scan, dim3(256), dim3(256), 0, stream, p);
}

// Round 8
// 1103.743 us; speedup vs baseline: 1.0728x; 1.0728x over previous
//
#include <hip/hip_runtime.h>
#include <math.h>

// BWNet scan v8: 8 fat scan blocks (was 32).
// Theory: per-step cost scales with participant count (2 global max-waits/step
// + MALL probe serialization over N producer lines). 8 blocks x 1024 key
// columns each (kslice in 128KB LDS), W_a0 slice (32 rows) + W_a3 + gates in
// VGPRs. Agent-scope tagged-word exchange (proven), 2 edges/step, fan-in 8.
// Phase B polls records AND all 8 cand columns concurrently (one poll round).
// k_init (256 blocks): keys GEMM + func_embed + pair zero + output zero.

typedef float v4f __attribute__((ext_vector_type(4)));
typedef unsigned long long ull;

#define N_ENT 8192
#define EMB   256
#define KD    32
#define ARD   1024
#define UT    233
#define NSCAN 8
#define COLS  1024   // key columns per scan block

// workspace float-index offsets
#define WS_KEYS 0         // 32*8192 floats, k-major: keys[k*8192+j]
#define WS_C0   262144    // 256: b_a0 + relu(W_fe@um + b_fe)
#define WS_PAIR 262400    // tagged-pair region (byte 1049600, 8B aligned)
#define PR_RI0  0         // 256 pairs: ri0[j], written by scan block j>>5
#define PR_PART 256       // 8 blocks * 40 pairs: [0]=psum [1]=pmax [2]=pidx [3..34]=cand
#define NPAIRS  (256 + 8 * 40)

struct Params {
  const float *um, *emask, *enc, *arin, *W_fe, *b_fe, *W_k, *b_k,
              *W_a0, *b_a0, *W_a1, *b_a1, *W_f, *b_f, *W_i0, *b_i0,
              *W_i1, *b_i1, *W_o, *b_o, *ln_g, *ln_b, *W_a3, *b_a3;
  const int* ct;
  float* out;
  float* wsf;
  int*   wsi;
};

__device__ __forceinline__ ull ld_pair(ull* p_) {
  return __hip_atomic_load(p_, __ATOMIC_RELAXED, __HIP_MEMORY_SCOPE_AGENT);
}
__device__ __forceinline__ void st_pair(ull* p_, ull v) {
  __hip_atomic_store(p_, v, __ATOMIC_RELAXED, __HIP_MEMORY_SCOPE_AGENT);
}
__device__ __forceinline__ ull packf(float v, unsigned tag) {
  return ((ull)tag << 32) | (ull)__float_as_uint(v);
}
__device__ __forceinline__ ull packi(int v, unsigned tag) {
  return ((ull)tag << 32) | (ull)(unsigned)v;
}
__device__ __forceinline__ unsigned ptag(ull u) { return (unsigned)(u >> 32); }
__device__ __forceinline__ float pvalf(ull u) { return __uint_as_float((unsigned)u); }

// LDS-only barrier: drains lgkmcnt but NOT vmcnt (global stores keep flying).
__device__ __forceinline__ void bar_lds() {
  asm volatile("s_waitcnt lgkmcnt(0)\n\ts_barrier" ::: "memory");
}

// ---------------- init: keys GEMM, func_embed, pair zero, OUTPUT ZERO ----------------
__global__ __launch_bounds__(256) void k_init(Params p) {
  __shared__ float enc_s[32 * 260];
  __shared__ float um_s[UT];
  const int tid = threadIdx.x, bid = blockIdx.x;
  float* keys = p.wsf + WS_KEYS;
  const size_t NN = (size_t)N_ENT * N_ENT;

  if (bid == 0 && tid < UT) um_s[tid] = p.um[tid];
  if (bid == 3) {  // zero all tag pairs (tag 0 matches no step tag 1..66)
    ull* pr = (ull*)(p.wsf + WS_PAIR);
    for (int i = tid; i < NPAIRS; i += 256) pr[i] = 0ull;
  }

  const int j0 = bid * 32;
  #pragma unroll
  for (int i = 0; i < 8; ++i) {
    int idx = i * 256 + tid;
    int row = idx >> 6, c4 = idx & 63;
    v4f v = *(const v4f*)(p.enc + (size_t)(j0 + row) * EMB + c4 * 4);
    *(v4f*)&enc_s[row * 260 + c4 * 4] = v;
  }
  __syncthreads();
  {
    const int jl = tid >> 3, kg = tid & 7;
    float acc[4];
    #pragma unroll
    for (int kk = 0; kk < 4; ++kk) acc[kk] = p.b_k[kg * 4 + kk];
    for (int e4 = 0; e4 < 64; ++e4) {
      v4f x = *(const v4f*)&enc_s[jl * 260 + e4 * 4];
      #pragma unroll
      for (int kk = 0; kk < 4; ++kk) {
        v4f w = *(const v4f*)(p.W_k + (size_t)(kg * 4 + kk) * EMB + e4 * 4);
        acc[kk] += x.x * w.x + x.y * w.y + x.z * w.z + x.w * w.w;
      }
    }
    const int j = j0 + jl;
    #pragma unroll
    for (int kk = 0; kk < 4; ++kk) keys[(size_t)(kg * 4 + kk) * N_ENT + j] = acc[kk];
  }
  if (bid == 0) {
    float a = p.b_fe[tid];
    const float* wr = p.W_fe + (size_t)tid * UT;
    for (int u = 0; u < UT; ++u) a += wr[u] * um_s[u];
    p.wsf[WS_C0 + tid] = fmaxf(a, 0.f) + p.b_a0[tid];
  }

  // zero the whole unit_logits region at full 256-block HBM bandwidth
  {
    v4f z = (v4f){0.f, 0.f, 0.f, 0.f};
    v4f* o4 = (v4f*)p.out;
    const size_t tot = NN / 4;
    for (size_t i = (size_t)bid * 256 + tid; i < tot; i += (size_t)256 * 256)
      __builtin_nontemporal_store(z, o4 + i);
  }
}

// ---------------- main: 8-block scan ----------------
__global__ __launch_bounds__(256, 1) void k_scan(Params p) {
  const int tid = threadIdx.x, bid = blockIdx.x;  // 0..7
  int ctv = p.ct[0];
  const int steps = ctv < 0 ? 0 : (ctv > 64 ? 64 : ctv);
  const size_t NN = (size_t)N_ENT * N_ENT;

  __shared__ float kslice[KD * COLS];     // 128 KB: this block's 1024 key cols, k-major
  __shared__ float ar2[8 * 132];          // ar, 8 chunks of 128, pad 132
  __shared__ float ri0f[256];
  __shared__ float cand_s[8 * 32];
  __shared__ unsigned maskb[256], selb[256];
  __shared__ float x_i1[32], q_s[32], h_s[32], qnf[32];
  __shared__ float garr[128], fog[32], rem[32], og[32];
  __shared__ float b_a1s[32], gb_s[128], lng_s[32], lnb_s[32], c0own[32];
  __shared__ float psums[8], pmaxs[8];
  __shared__ int   pidxs[8];
  __shared__ float reds[4], rmaxs[4];
  __shared__ int   ridxs[4];
  __shared__ int   done_s;

  ull* ri0p  = (ull*)(p.wsf + WS_PAIR) + PR_RI0;
  ull* partp = (ull*)(p.wsf + WS_PAIR) + PR_PART;
  const float* keys = p.wsf + WS_KEYS;

  // ---- preamble: replicated state + weights into LDS / registers ----
  for (int idx = tid; idx < KD * COLS; idx += 256) {
    const int k = idx >> 10, j = idx & (COLS - 1);
    kslice[idx] = keys[(size_t)k * N_ENT + bid * COLS + j];
  }
  for (int i = tid; i < ARD; i += 256) ar2[(i >> 7) * 132 + (i & 127)] = p.arin[i];
  {
    unsigned mb = 0u;
    const float* em = p.emask + (size_t)tid * 32;
    #pragma unroll
    for (int j = 0; j < 32; ++j) mb |= (em[j] != 0.f) ? (1u << j) : 0u;
    maskb[tid] = mb; selb[tid] = 0u;
  }
  if (tid < 32) {
    b_a1s[tid] = p.b_a1[tid];
    lng_s[tid] = p.ln_g[tid]; lnb_s[tid] = p.ln_b[tid];
    q_s[tid] = 0.f; h_s[tid] = 0.f; qnf[tid] = 0.f; x_i1[tid] = 0.f;
    c0own[tid] = p.wsf[WS_C0 + bid * 32 + tid];
  }
  if (tid < 128) {
    const int g = tid >> 5, r = tid & 31;
    const float* bg = (g == 0) ? p.b_f : (g == 1) ? p.b_i0 : (g == 2) ? p.b_i1 : p.b_o;
    gb_s[tid] = bg[r];
  }
  if (tid == 0) done_s = 0;

  v4f w0[32];  // W_a0 rows [32b,32b+32): thread = (row tid>>3, cols (tid&7)*128..+128)
  { const float* s = p.W_a0 + (size_t)(bid * 32 + (tid >> 3)) * ARD + (tid & 7) * 128;
    #pragma unroll
    for (int i = 0; i < 32; ++i) w0[i] = ((const v4f*)s)[i]; }
  v4f w1[8];   // W_a1: thread = (row tid>>3, cols (tid&7)*32..+32)
  { const float* s = p.W_a1 + (size_t)(tid >> 3) * EMB + (tid & 7) * 32;
    #pragma unroll
    for (int i = 0; i < 8; ++i) w1[i] = ((const v4f*)s)[i]; }
  v4f wg[8];   // LSTM gates: 128 rows x 2 halves
  { const int rowg = tid >> 1, g = rowg >> 5, r = rowg & 31, half = tid & 1;
    const float* W = (g == 0) ? p.W_f : (g == 1) ? p.W_i0 : (g == 2) ? p.W_i1 : p.W_o;
    const float* s = W + r * 64 + half * 32;
    #pragma unroll
    for (int i = 0; i < 8; ++i) wg[i] = ((const v4f*)s)[i]; }
  v4f w3[32];  // W_a3 rows {tid, tid+256, tid+512, tid+768}
  float b3[4];
  #pragma unroll
  for (int rr = 0; rr < 4; ++rr) {
    const float* s = p.W_a3 + (size_t)(tid + 256 * rr) * KD;
    #pragma unroll
    for (int i = 0; i < 8; ++i) w3[rr * 8 + i] = ((const v4f*)s)[i];
    b3[rr] = p.b_a3[tid + 256 * rr];
  }
  __syncthreads();

  // produce ri0 rows [32b,32b+32) from LDS ar
  auto produce = [&](unsigned tag) {
    const int rl = tid >> 3, seg = tid & 7;
    const float* a = &ar2[seg * 132];
    float pa = 0.f;
    #pragma unroll
    for (int i = 0; i < 32; ++i) {
      v4f av = *(const v4f*)(a + 4 * i);
      pa += w0[i].x * av.x + w0[i].y * av.y + w0[i].z * av.z + w0[i].w * av.w;
    }
    #pragma unroll
    for (int m = 4; m; m >>= 1) pa += __shfl_xor(pa, m);
    if (seg == 0)
      st_pair(&ri0p[bid * 32 + rl], packf(fmaxf(pa + c0own[rl], 0.f), tag));
  };
  produce(1u);  // ri0 for step 0

  for (int t = 0; t < steps; ++t) {
    const unsigned tg = (unsigned)(t + 1);

    // ==== Phase A1: first wave polls ri0 (4 tags/lane), stages to LDS ====
    if (tid < 64) {
      ull u0, u1, u2, u3; int guard = 0;
      for (;;) {
        u0 = ld_pair(&ri0p[tid]);
        u1 = ld_pair(&ri0p[tid + 64]);
        u2 = ld_pair(&ri0p[tid + 128]);
        u3 = ld_pair(&ri0p[tid + 192]);
        if ((ptag(u0) == tg) && (ptag(u1) == tg) && (ptag(u2) == tg) && (ptag(u3) == tg)) break;
        if (++guard > (1 << 20)) break;  // failsafe: never hang
        __builtin_amdgcn_s_sleep(1);
      }
      ri0f[tid] = pvalf(u0); ri0f[tid + 64] = pvalf(u1);
      ri0f[tid + 128] = pvalf(u2); ri0f[tid + 192] = pvalf(u3);
    }
    bar_lds();
    const int act = (done_s == 0);

    // ==== i1 = relu(W_a1 @ ri0 + b_a1) ====
    {
      const int r = tid >> 3, s8 = tid & 7;
      float p1 = 0.f;
      #pragma unroll
      for (int i = 0; i < 8; ++i) {
        v4f xv = *(const v4f*)&ri0f[s8 * 32 + 4 * i];
        p1 += w1[i].x * xv.x + w1[i].y * xv.y + w1[i].z * xv.z + w1[i].w * xv.w;
      }
      #pragma unroll
      for (int m = 4; m; m >>= 1) p1 += __shfl_xor(p1, m);
      if (s8 == 0) x_i1[r] = fmaxf(p1 + b_a1s[r], 0.f);
    }
    bar_lds();
    // ==== 4 gate pre-activations ====
    {
      const int rowg = tid >> 1, g = rowg >> 5, half = tid & 1;
      const float* xsrc = half ? q_s : x_i1;  // x = concat(i1, q)
      float pg = 0.f;
      #pragma unroll
      for (int i = 0; i < 8; ++i)
        pg += wg[i].x * xsrc[4 * i] + wg[i].y * xsrc[4 * i + 1] +
              wg[i].z * xsrc[4 * i + 2] + wg[i].w * xsrc[4 * i + 3];
      pg += __shfl_xor(pg, 1);
      if (!half) {
        pg += gb_s[rowg];
        garr[rowg] = (g == 2) ? tanhf(pg) : 1.f / (1.f + __expf(-pg));
      }
    }
    bar_lds();
    // ==== 3 layernorms in parallel (one per wave) ====
    {
      const int w = tid >> 6, k = tid & 63;
      if (w < 3 && k < 32) {
        float a = (w == 0) ? garr[k] : (w == 1) ? garr[32 + k] * garr[64 + k] : garr[96 + k];
        float s = a;
        #pragma unroll
        for (int m = 16; m; m >>= 1) s += __shfl_xor(s, m);
        const float mean = s * (1.f / 32.f);
        const float d = a - mean;
        float vv = d * d;
        #pragma unroll
        for (int m = 16; m; m >>= 1) vv += __shfl_xor(vv, m);
        vv *= (1.f / 32.f);
        const float y = d * rsqrtf(vv + 1e-5f) * lng_s[k] + lnb_s[k];
        if (w == 0) fog[k] = y; else if (w == 1) rem[k] = y; else og[k] = y;
      }
    }
    bar_lds();
    if (tid < 32) {
      const float nh = rem[tid] + fog[tid] * h_s[tid];
      const float qv = tanhf(nh) * og[tid];
      qnf[tid] = qv;
      if (act) { h_s[tid] = nh; q_s[tid] = qv; }
    }
    bar_lds();

    // ==== sweep: 4 columns per thread from LDS kslice ====
    float vr[4];
    float sv, mv; int mi;
    {
      float dot0 = 0.f;
      #pragma unroll
      for (int k = 0; k < 32; ++k) dot0 += qnf[k] * kslice[k * COLS + tid];
      vr[0] = __expf(__logf(1.f / (1.f + __expf(-dot0))) / 0.8f);
      sv = vr[0]; mv = vr[0]; mi = bid * COLS + tid;
      #pragma unroll
      for (int c = 1; c < 4; ++c) {
        const int jl = tid + 256 * c;
        float dot = 0.f;
        #pragma unroll
        for (int k = 0; k < 32; ++k) dot += qnf[k] * kslice[k * COLS + jl];
        const float v = __expf(__logf(1.f / (1.f + __expf(-dot))) / 0.8f);
        vr[c] = v;
        sv += v;
        const int jg = bid * COLS + jl;
        if (v > mv || (v == mv && jg < mi)) { mv = v; mi = jg; }
      }
      #pragma unroll
      for (int m = 32; m; m >>= 1) {
        sv += __shfl_xor(sv, m);
        const float ov = __shfl_xor(mv, m);
        const int oi = __shfl_xor(mi, m);
        if (ov > mv || (ov == mv && oi < mi)) { mv = ov; mi = oi; }
      }
      const int wv = tid >> 6;
      if ((tid & 63) == 0) { reds[wv] = sv; rmaxs[wv] = mv; ridxs[wv] = mi; }
    }
    bar_lds();
    // ==== block combine (all threads) + ship record & cand column ====
    {
      const float Sb = ((reds[0] + reds[1]) + reds[2]) + reds[3];
      float Mb = rmaxs[0]; int Ib = ridxs[0];
      #pragma unroll
      for (int i2 = 1; i2 < 4; ++i2)
        if (rmaxs[i2] > Mb || (rmaxs[i2] == Mb && ridxs[i2] < Ib)) { Mb = rmaxs[i2]; Ib = ridxs[i2]; }
      ull* rec = &partp[bid * 40];
      if (tid == 0) {
        st_pair(&rec[0], packf(Sb, tg));
        st_pair(&rec[1], packf(Mb, tg));
        st_pair(&rec[2], packi(Ib, tg));
      }
      if (tid < 32 && (Ib >> 10) == bid)
        st_pair(&rec[3 + tid], packf(kslice[tid * COLS + (Ib & (COLS - 1))], tg));
    }

    // ==== Phase B: poll records + ALL cand columns concurrently ====
    {
      const int b = tid >> 5, k = tid & 31;
      ull* cp = &partp[b * 40 + 3 + k];
      ull* rp = &partp[tid * 40];        // valid only for tid<8
      const bool sc = (tid < 8);
      ull uc, u0 = 0, u1 = 0, u2 = 0;
      int guard = 0;
      for (;;) {
        uc = ld_pair(cp);
        bool ok = (ptag(uc) == tg);
        if (sc) {
          u0 = ld_pair(&rp[0]); u1 = ld_pair(&rp[1]); u2 = ld_pair(&rp[2]);
          ok = ok & (ptag(u0) == tg) & (ptag(u1) == tg) & (ptag(u2) == tg);
        }
        if (ok) break;
        if (++guard > (1 << 20)) break;
        __builtin_amdgcn_s_sleep(1);
      }
      cand_s[b * 32 + k] = pvalf(uc);
      if (sc) { psums[tid] = pvalf(u0); pmaxs[tid] = pvalf(u1); pidxs[tid] = (int)(unsigned)u2; }
    }
    bar_lds();
    // ==== all threads redundantly: global reduce + cent + delta + flags ====
    float S = psums[0], M = pmaxs[0]; int I = pidxs[0];
    #pragma unroll
    for (int b2 = 1; b2 < 8; ++b2) {
      S += psums[b2];
      const float mb_ = pmaxs[b2]; const int ib_ = pidxs[b2];
      if (mb_ > M || (mb_ == M && ib_ < I)) { M = mb_; I = ib_; }
    }
    const int cb = I >> 10;
    float cw[32], sm = 0.f;
    #pragma unroll
    for (int g2 = 0; g2 < 8; ++g2) {
      v4f x = *(const v4f*)&cand_s[cb * 32 + 4 * g2];
      cw[4 * g2] = x.x; cw[4 * g2 + 1] = x.y; cw[4 * g2 + 2] = x.z; cw[4 * g2 + 3] = x.w;
      sm += (x.x + x.y) + (x.z + x.w);
    }
    const float mean = sm * (1.f / 32.f);
    int nanf = 0;
    float dl0 = b3[0], dl1 = b3[1], dl2 = b3[2], dl3 = b3[3];
    #pragma unroll
    for (int c = 0; c < 32; ++c) {
      const float cv = cw[c] - mean;
      nanf |= (cv != cv) ? 1 : 0;
      dl0 += w3[c >> 2][c & 3] * cv;
      dl1 += w3[8 + (c >> 2)][c & 3] * cv;
      dl2 += w3[16 + (c >> 2)][c & 3] * cv;
      dl3 += w3[24 + (c >> 2)][c & 3] * cv;
    }
    const unsigned mw = maskb[I >> 5];
    const int valid = (S != 0.f) ? 1 : 0;
    const int hit = (act && valid && ((mw >> (I & 31)) & 1)) ? 1 : 0;
    const int nf = nanf ? 0 : 1;
    // row write for step t (4 cols/thread; never drained in-loop)
    {
      const float inv = (act && valid) ? (1.f / S) : 0.f;
      float* orow = p.out + (size_t)t * N_ENT + bid * COLS;
      #pragma unroll
      for (int c = 0; c < 4; ++c)
        __builtin_nontemporal_store((act && valid) ? vr[c] * inv : 0.f, orow + 256 * c + tid);
    }
    if (hit && nf) {  // replicated ar update: 4 rows/thread
      if (dl0 > 0.f) ar2[(tid >> 7) * 132 + (tid & 127)] += dl0;
      const int r1 = tid + 256, r2 = tid + 512, r3 = tid + 768;
      if (dl1 > 0.f) ar2[(r1 >> 7) * 132 + (r1 & 127)] += dl1;
      if (dl2 > 0.f) ar2[(r2 >> 7) * 132 + (r2 & 127)] += dl2;
      if (dl3 > 0.f) ar2[(r3 >> 7) * 132 + (r3 & 127)] += dl3;
    }
    bar_lds();
    produce(tg + 1u);  // ri0 for step t+1 (most urgent stores first)
    if (tid == 0 && hit) {  // state updates; ordered before next reads by A1 bar
      maskb[I >> 5] = mw & ~(1u << (I & 31));
      selb[I >> 5] |= (1u << (I & 31));
      if (!nf) done_s = 1;
    }
  }
  __syncthreads();

  // ==== epilogue: sel_out and ar_out (replicated state) ====
  if (bid == 0) {
    for (int i = tid; i < N_ENT; i += 256)
      p.out[NN + i] = ((selb[i >> 5] >> (i & 31)) & 1u) ? 1.f : 0.f;
  } else if (bid == 1) {
    for (int i = tid; i < ARD; i += 256)
      p.out[NN + N_ENT + i] = ar2[(i >> 7) * 132 + (i & 127)];
  }
}

extern "C" void kernel_launch(void* const* d_in, const int* in_sizes, int n_in,
                              void* d_out, int out_size, void* d_ws, size_t ws_size,
                              hipStream_t stream) {
  (void)in_sizes; (void)n_in; (void)out_size; (void)ws_size;
  Params p;
  p.um    = (const float*)d_in[0];
  p.emask = (const float*)d_in[1];
  p.enc   = (const float*)d_in[2];
  p.arin  = (const float*)d_in[3];
  p.W_fe  = (const float*)d_in[4];
  p.b_fe  = (const float*)d_in[5];
  p.W_k   = (const float*)d_in[6];
  p.b_k   = (const float*)d_in[7];
  p.W_a0  = (const float*)d_in[8];
  p.b_a0  = (const float*)d_in[9];
  p.W_a1  = (const float*)d_in[10];
  p.b_a1  = (const float*)d_in[11];
  p.W_f   = (const float*)d_in[12];
  p.b_f   = (const float*)d_in[13];
  p.W_i0  = (const float*)d_in[14];
  p.b_i0  = (const float*)d_in[15];
  p.W_i1  = (const float*)d_in[16];
  p.b_i1  = (const float*)d_in[17];
  p.W_o   = (const float*)d_in[18];
  p.b_o   = (const float*)d_in[19];
  p.ln_g  = (const float*)d_in[20];
  p.ln_b  = (const float*)d_in[21];
  p.W_a3  = (const float*)d_in[22];
  p.b_a3  = (const float*)d_in[23];
  p.ct    = (const int*)d_in[24];
  p.out   = (float*)d_out;
  p.wsf   = (float*)d_ws;
  p.wsi   = (int*)d_ws;

  hipLaunchKernelGGL(k_init, dim3(256), dim3(256), 0, stream, p);
  hipLaunchKernelGGL(k_scan, dim3(NSCAN), dim3(256), 0, stream, p);
}

// Round 10
// 881.112 us; speedup vs baseline: 1.3439x; 1.2527x over previous
//
#include <hip/hip_runtime.h>
#include <math.h>

// BWNet scan v10: v2 structure (best-known: 620us scan / 943us total) with the
// exchange replaced by counter-gated atomic fan-in:
//  - sweep partials: atomicAdd(S_acc[t]) + atomicMax(Kmax[t], (v_bits<<32)|~idx)
//    + vmcnt(0) + atomicAdd(ctr_part[t]). Consumers poll ONE line (counter),
//    then read 2 lines. Winner's key column gathered from read-only keys[]
//    (plain cached loads) -- candidate-ship edge deleted.
//  - ri0: producers store 8 untagged words into a step-parity ping-pong slot,
//    __syncthreads (vmcnt drain), tid0 bumps ctr_ri0[t+1]. Consumers poll the
//    counter then batch-read 256 words.
// Everything else (LSTM phases, barriers, zero-role overlap, s_sleep polls,
// W_a3-from-global ar update, epilogue) is v2 verbatim.

typedef float v4f __attribute__((ext_vector_type(4)));
typedef unsigned long long ull;

#define N_ENT 8192
#define EMB   256
#define KD    32
#define ARD   1024
#define UT    233
#define NSCAN 32
#define NZERO 224
#define NBLK  256

// workspace float-index offsets
#define WS_KEYS 0         // 32*8192 floats, k-major: keys[k*8192+j]
#define WS_C0   262144    // 256: b_a0 + relu(W_fe@um + b_fe)
#define WS_PAIR 262400    // ull region (byte 1049600, 8B aligned)
// ull indices within the pair region
#define PR_RI0W  0        // 2*256: ri0 value words, ping-pong by step parity
#define PR_CRI0  512      // 65: ri0 completion counters (step t)
#define PR_CPART 577      // 64: partials completion counters
#define PR_KMAX  641      // 64: encoded argmax (v_bits<<32 | (0xFFFFFFFF-idx))
#define PR_SACC  705      // 32 ulls = 64 floats: S accumulators
#define NPAIRS   737

struct Params {
  const float *um, *emask, *enc, *arin, *W_fe, *b_fe, *W_k, *b_k,
              *W_a0, *b_a0, *W_a1, *b_a1, *W_f, *b_f, *W_i0, *b_i0,
              *W_i1, *b_i1, *W_o, *b_o, *ln_g, *ln_b, *W_a3, *b_a3;
  const int* ct;
  float* out;
  float* wsf;
  int*   wsi;
};

__device__ __forceinline__ ull ld_pair(ull* p_) {
  return __hip_atomic_load(p_, __ATOMIC_RELAXED, __HIP_MEMORY_SCOPE_AGENT);
}
__device__ __forceinline__ void st_pair(ull* p_, ull v) {
  __hip_atomic_store(p_, v, __ATOMIC_RELAXED, __HIP_MEMORY_SCOPE_AGENT);
}
__device__ __forceinline__ void wait_ctr(ull* c, ull target) {
  int guard = 0;
  while (__hip_atomic_load(c, __ATOMIC_RELAXED, __HIP_MEMORY_SCOPE_AGENT) < target) {
    __builtin_amdgcn_s_sleep(1);
    if (++guard > (1 << 20)) break;  // failsafe: never hang
  }
}

// ---------------- init: keys GEMM, func_embed, pair-region zero ----------------
__global__ __launch_bounds__(256) void k_init(Params p) {
  __shared__ float enc_s[32 * 260];
  __shared__ float um_s[UT];
  const int tid = threadIdx.x, bid = blockIdx.x;
  float* keys = p.wsf + WS_KEYS;

  if (bid == 0 && tid < UT) um_s[tid] = p.um[tid];
  if (bid == 3) {  // zero ri0 slots, counters, Kmax, S accumulators
    ull* pr = (ull*)(p.wsf + WS_PAIR);
    for (int i = tid; i < NPAIRS; i += 256) pr[i] = 0ull;
  }

  const int j0 = bid * 32;
  #pragma unroll
  for (int i = 0; i < 8; ++i) {
    int idx = i * 256 + tid;
    int row = idx >> 6, c4 = idx & 63;
    v4f v = *(const v4f*)(p.enc + (size_t)(j0 + row) * EMB + c4 * 4);
    *(v4f*)&enc_s[row * 260 + c4 * 4] = v;
  }
  __syncthreads();
  {
    const int jl = tid >> 3, kg = tid & 7;
    float acc[4];
    #pragma unroll
    for (int kk = 0; kk < 4; ++kk) acc[kk] = p.b_k[kg * 4 + kk];
    for (int e4 = 0; e4 < 64; ++e4) {
      v4f x = *(const v4f*)&enc_s[jl * 260 + e4 * 4];
      #pragma unroll
      for (int kk = 0; kk < 4; ++kk) {
        v4f w = *(const v4f*)(p.W_k + (size_t)(kg * 4 + kk) * EMB + e4 * 4);
        acc[kk] += x.x * w.x + x.y * w.y + x.z * w.z + x.w * w.w;
      }
    }
    const int j = j0 + jl;
    #pragma unroll
    for (int kk = 0; kk < 4; ++kk) keys[(size_t)(kg * 4 + kk) * N_ENT + j] = acc[kk];
  }
  if (bid == 0) {
    float a = p.b_fe[tid];
    const float* wr = p.W_fe + (size_t)tid * UT;
    for (int u = 0; u < UT; ++u) a += wr[u] * um_s[u];
    p.wsf[WS_C0 + tid] = fmaxf(a, 0.f) + p.b_a0[tid];
  }
}

// ---------------- main: scan (blocks 0..31) + output zeroing (32..255) ----------------
__global__ __launch_bounds__(256, 1) void k_scan(Params p) {
  const int tid = threadIdx.x, bid = blockIdx.x;
  int ctv = p.ct[0];
  const int steps = ctv < 0 ? 0 : (ctv > 64 ? 64 : ctv);
  const size_t NN = (size_t)N_ENT * N_ENT;

  if (bid >= NSCAN) {  // -------- zero role (overlaps the scan; v2-proven) --------
    v4f z = (v4f){0.f, 0.f, 0.f, 0.f};
    v4f* o4 = (v4f*)p.out;
    const size_t tot = NN / 4;
    for (size_t i = (size_t)steps * (N_ENT / 4) + (size_t)(bid - NSCAN) * 256 + tid;
         i < tot; i += (size_t)NZERO * 256)
      __builtin_nontemporal_store(z, o4 + i);
    return;
  }

  // -------- scan role --------
  __shared__ float ar_s[32 * 33];
  __shared__ float ri0_s[8 * 33];
  __shared__ unsigned maskb[256], selb[256];
  __shared__ float x_i1[32], q_s[32], h_s[32], qnf[32];
  __shared__ float garr[128], fog[32], rem[32], og[32], cent[32];
  __shared__ float b_a1s[32], gb_s[128], lng_s[32], lnb_s[32], c0own[8];
  __shared__ float reds[4], rmaxs[4];
  __shared__ int   ridxs[4];
  __shared__ float ssum_s;
  __shared__ int   upd_s, done_s;

  ull*   pairb = (ull*)(p.wsf + WS_PAIR);
  ull*   ri0w  = pairb + PR_RI0W;
  ull*   cri0  = pairb + PR_CRI0;
  ull*   cpart = pairb + PR_CPART;
  ull*   kmaxp = pairb + PR_KMAX;
  float* saccp = (float*)(pairb + PR_SACC);
  const float* keys = p.wsf + WS_KEYS;

  // ---- preamble: replicated state + weights into LDS / registers (v2) ----
  for (int i = tid; i < ARD; i += 256) ar_s[(i >> 5) * 33 + (i & 31)] = p.arin[i];
  {
    unsigned mb = 0u;
    const float* em = p.emask + (size_t)tid * 32;
    #pragma unroll
    for (int j = 0; j < 32; ++j) mb |= (em[j] != 0.f) ? (1u << j) : 0u;
    maskb[tid] = mb; selb[tid] = 0u;
  }
  if (tid < 32) {
    b_a1s[tid] = p.b_a1[tid];
    lng_s[tid] = p.ln_g[tid]; lnb_s[tid] = p.ln_b[tid];
    q_s[tid] = 0.f; h_s[tid] = 0.f; qnf[tid] = 0.f; x_i1[tid] = 0.f;
  }
  if (tid < 128) {
    const int g = tid >> 5, r = tid & 31;
    const float* bg = (g == 0) ? p.b_f : (g == 1) ? p.b_i0 : (g == 2) ? p.b_i1 : p.b_o;
    gb_s[tid] = bg[r];
  }
  if (tid < 8) c0own[tid] = p.wsf[WS_C0 + bid * 8 + tid];
  if (tid == 0) done_s = 0;

  v4f w0[8];  // W_a0 rows [8b,8b+8): thread = (row tid>>5, cols (tid&31)*32..+32)
  { const float* s = p.W_a0 + (size_t)(bid * 8 + (tid >> 5)) * ARD + (tid & 31) * 32;
    #pragma unroll
    for (int i = 0; i < 8; ++i) w0[i] = ((const v4f*)s)[i]; }
  v4f w1[8];  // W_a1: thread = (row tid>>3, cols (tid&7)*32..+32)
  { const float* s = p.W_a1 + (size_t)(tid >> 3) * EMB + (tid & 7) * 32;
    #pragma unroll
    for (int i = 0; i < 8; ++i) w1[i] = ((const v4f*)s)[i]; }
  v4f wg[8];  // LSTM gates: 128 rows x 2 halves
  { const int rowg = tid >> 1, g = rowg >> 5, r = rowg & 31, half = tid & 1;
    const float* W = (g == 0) ? p.W_f : (g == 1) ? p.W_i0 : (g == 2) ? p.W_i1 : p.W_o;
    const float* s = W + r * 64 + half * 32;
    #pragma unroll
    for (int i = 0; i < 8; ++i) wg[i] = ((const v4f*)s)[i]; }
  float kc[32];  // this thread's key column, register-resident
  { const int gcol = bid * 256 + tid;
    #pragma unroll
    for (int k = 0; k < 32; ++k) kc[k] = keys[(size_t)k * N_ENT + gcol]; }
  __syncthreads();

  // produce ri0 slice for step tt into slot[tt&1] (8 rows owned by this block)
  auto produce = [&](int tt) {
    const int seg = tid & 31, rl = tid >> 5;
    const float* a = &ar_s[seg * 33];
    float pa = 0.f;
    #pragma unroll
    for (int i = 0; i < 8; ++i) {
      v4f av = *(const v4f*)(a + 4 * i);
      pa += w0[i].x * av.x + w0[i].y * av.y + w0[i].z * av.z + w0[i].w * av.w;
    }
    #pragma unroll
    for (int m = 16; m; m >>= 1) pa += __shfl_xor(pa, m);
    if (seg == 0)
      st_pair(&ri0w[(tt & 1) * 256 + bid * 8 + rl],
              (ull)__float_as_uint(fmaxf(pa + c0own[rl], 0.f)));
  };
  produce(0);
  __syncthreads();  // drains vmcnt -> ri0 stores visible before counter bump
  if (tid == 0)
    __hip_atomic_fetch_add(&cri0[0], 1ull, __ATOMIC_RELAXED, __HIP_MEMORY_SCOPE_AGENT);

  float v_reg = 0.f;
  for (int t = 0; t < steps; ++t) {
    // ==== Phase A: wait ri0 counter -> batch read -> LSTM chain (v2) ====
    if (tid == 0) wait_ctr(&cri0[t], (ull)NSCAN);
    __syncthreads();
    {
      ull u = ld_pair(&ri0w[(t & 1) * 256 + tid]);
      ri0_s[(tid >> 5) * 33 + (tid & 31)] = __uint_as_float((unsigned)u);
    }
    __syncthreads();
    const int act = (done_s == 0);
    {  // i1 = relu(W_a1 @ ri0 + b_a1)
      const int r = tid >> 3, s8 = tid & 7;
      float p1 = 0.f;
      #pragma unroll
      for (int i = 0; i < 8; ++i) {
        const float* xx = &ri0_s[s8 * 33 + 4 * i];
        p1 += w1[i].x * xx[0] + w1[i].y * xx[1] + w1[i].z * xx[2] + w1[i].w * xx[3];
      }
      #pragma unroll
      for (int m = 4; m; m >>= 1) p1 += __shfl_xor(p1, m);
      if (s8 == 0) x_i1[r] = fmaxf(p1 + b_a1s[r], 0.f);
    }
    __syncthreads();
    {  // 4 gate pre-activations
      const int rowg = tid >> 1, g = rowg >> 5, half = tid & 1;
      const float* xsrc = half ? q_s : x_i1;  // x = concat(i1, q)
      float pg = 0.f;
      #pragma unroll
      for (int i = 0; i < 8; ++i)
        pg += wg[i].x * xsrc[4 * i] + wg[i].y * xsrc[4 * i + 1] +
              wg[i].z * xsrc[4 * i + 2] + wg[i].w * xsrc[4 * i + 3];
      pg += __shfl_xor(pg, 1);
      if (!half) {
        pg += gb_s[rowg];
        garr[rowg] = (g == 2) ? tanhf(pg) : 1.f / (1.f + __expf(-pg));
      }
    }
    __syncthreads();
    {  // 3 layernorms in parallel (one per wave)
      const int w = tid >> 6, k = tid & 63;
      if (w < 3 && k < 32) {
        float a = (w == 0) ? garr[k] : (w == 1) ? garr[32 + k] * garr[64 + k] : garr[96 + k];
        float s = a;
        #pragma unroll
        for (int m = 16; m; m >>= 1) s += __shfl_xor(s, m);
        const float mean = s * (1.f / 32.f);
        const float d = a - mean;
        float vv = d * d;
        #pragma unroll
        for (int m = 16; m; m >>= 1) vv += __shfl_xor(vv, m);
        vv *= (1.f / 32.f);
        const float y = d * rsqrtf(vv + 1e-5f) * lng_s[k] + lnb_s[k];
        if (w == 0) fog[k] = y; else if (w == 1) rem[k] = y; else og[k] = y;
      }
    }
    __syncthreads();
    if (tid < 32) {
      const float nh = rem[tid] + fog[tid] * h_s[tid];
      const float qv = tanhf(nh) * og[tid];
      qnf[tid] = qv;
      if (act) { h_s[tid] = nh; q_s[tid] = qv; }
    }
    __syncthreads();

    // ==== Phase S: sweep over this block's 256 register-resident key cols ====
    {
      float dot = 0.f;
      #pragma unroll
      for (int k = 0; k < 32; ++k) dot += qnf[k] * kc[k];
      const float sig = 1.f / (1.f + __expf(-dot));
      const float v = __expf(__logf(sig) / 0.8f);  // sig^(1/TEMP)
      v_reg = v;
      float sv = v, mv = v;
      int mi = (bid << 8) + tid;
      #pragma unroll
      for (int m = 32; m; m >>= 1) {
        sv += __shfl_xor(sv, m);
        const float ov = __shfl_xor(mv, m);
        const int oi = __shfl_xor(mi, m);
        if (ov > mv || (ov == mv && oi < mi)) { mv = ov; mi = oi; }
      }
      const int wv = tid >> 6;
      if ((tid & 63) == 0) { reds[wv] = sv; rmaxs[wv] = mv; ridxs[wv] = mi; }
    }
    __syncthreads();
    if (tid == 0) {  // atomic fan-in: S add, argmax max, then counter bump
      float Sb = ((reds[0] + reds[1]) + reds[2]) + reds[3];
      float Mb = rmaxs[0]; int Ib = ridxs[0];
      #pragma unroll
      for (int i2 = 1; i2 < 4; ++i2)
        if (rmaxs[i2] > Mb || (rmaxs[i2] == Mb && ridxs[i2] < Ib)) { Mb = rmaxs[i2]; Ib = ridxs[i2]; }
      __hip_atomic_fetch_add(&saccp[t], Sb, __ATOMIC_RELAXED, __HIP_MEMORY_SCOPE_AGENT);
      const ull key = ((ull)__float_as_uint(Mb) << 32) | (ull)(0xFFFFFFFFu - (unsigned)Ib);
      __hip_atomic_fetch_max(&kmaxp[t], key, __ATOMIC_RELAXED, __HIP_MEMORY_SCOPE_AGENT);
      asm volatile("s_waitcnt vmcnt(0)" ::: "memory");  // data before flag
      __hip_atomic_fetch_add(&cpart[t], 1ull, __ATOMIC_RELAXED, __HIP_MEMORY_SCOPE_AGENT);
    }

    // ==== Phase B: one-line wait -> 2-line read -> keys gather -> flags ====
    if (tid == 0) wait_ctr(&cpart[t], (ull)NSCAN);
    __syncthreads();
    if (tid < 32) {
      const float s = __hip_atomic_load(&saccp[t], __ATOMIC_RELAXED, __HIP_MEMORY_SCOPE_AGENT);
      const ull km = ld_pair(&kmaxp[t]);
      const int ii = (int)(0xFFFFFFFFu - (unsigned)(km & 0xFFFFFFFFull));
      const float kv = keys[(size_t)tid * N_ENT + ii];  // keys[:, pick], read-only
      float mn = kv;
      #pragma unroll
      for (int mm = 16; mm; mm >>= 1) mn += __shfl_xor(mn, mm);
      mn *= (1.f / 32.f);
      const float cv = kv - mn;
      cent[tid] = cv;
      const unsigned long long bb = __ballot(cv != cv);
      if (tid == 0) {
        const int valid = (s != 0.f);
        const int nf = (bb == 0) ? 1 : 0;
        const unsigned mw = maskb[ii >> 5];
        const int hit = (act && valid && ((mw >> (ii & 31)) & 1)) ? 1 : 0;
        ssum_s = s;
        upd_s = (hit && nf) ? 1 : 0;
        if (hit) {
          maskb[ii >> 5] = mw & ~(1u << (ii & 31));
          selb[ii >> 5] |= (1u << (ii & 31));
          if (!nf) done_s = 1;
        }
      }
    }
    __syncthreads();
    {  // row write for step t (this block's 256 columns)
      const float S = ssum_s;
      const float rowv = (act && (S != 0.f)) ? (v_reg / S) : 0.f;
      __builtin_nontemporal_store(rowv, p.out + (size_t)t * N_ENT + (bid << 8) + tid);
    }
    if (upd_s) {  // replicated ar update: 4 rows/thread, W_a3 from L2 (v2)
      #pragma unroll
      for (int rr = 0; rr < 4; ++rr) {
        const int r = tid + rr * 256;
        const float* wr = p.W_a3 + (size_t)r * KD;
        float dl = p.b_a3[r];
        #pragma unroll
        for (int c4 = 0; c4 < 8; ++c4) {
          v4f wv4 = *(const v4f*)(wr + 4 * c4);
          dl += wv4.x * cent[4 * c4] + wv4.y * cent[4 * c4 + 1] +
                wv4.z * cent[4 * c4 + 2] + wv4.w * cent[4 * c4 + 3];
        }
        if (dl > 0.f) ar_s[(r >> 5) * 33 + (r & 31)] += dl;
      }
    }
    __syncthreads();
    produce(t + 1);   // ri0 for step t+1 into slot[(t+1)&1]
    __syncthreads();  // drains vmcnt -> slice visible before counter bump
    if (tid == 0)
      __hip_atomic_fetch_add(&cri0[t + 1], 1ull, __ATOMIC_RELAXED, __HIP_MEMORY_SCOPE_AGENT);
  }
  __syncthreads();

  // ==== epilogue: sel_out and ar_out (replicated state) ====
  if (bid == 0) {
    for (int i = tid; i < N_ENT; i += 256)
      p.out[NN + i] = ((selb[i >> 5] >> (i & 31)) & 1u) ? 1.f : 0.f;
  } else if (bid == 1) {
    for (int i = tid; i < ARD; i += 256)
      p.out[NN + N_ENT + i] = ar_s[(i >> 5) * 33 + (i & 31)];
  }
}

extern "C" void kernel_launch(void* const* d_in, const int* in_sizes, int n_in,
                              void* d_out, int out_size, void* d_ws, size_t ws_size,
                              hipStream_t stream) {
  (void)in_sizes; (void)n_in; (void)out_size; (void)ws_size;
  Params p;
  p.um    = (const float*)d_in[0];
  p.emask = (const float*)d_in[1];
  p.enc   = (const float*)d_in[2];
  p.arin  = (const float*)d_in[3];
  p.W_fe  = (const float*)d_in[4];
  p.b_fe  = (const float*)d_in[5];
  p.W_k   = (const float*)d_in[6];
  p.b_k   = (const float*)d_in[7];
  p.W_a0  = (const float*)d_in[8];
  p.b_a0  = (const float*)d_in[9];
  p.W_a1  = (const float*)d_in[10];
  p.b_a1  = (const float*)d_in[11];
  p.W_f   = (const float*)d_in[12];
  p.b_f   = (const float*)d_in[13];
  p.W_i0  = (const float*)d_in[14];
  p.b_i0  = (const float*)d_in[15];
  p.W_i1  = (const float*)d_in[16];
  p.b_i1  = (const float*)d_in[17];
  p.W_o   = (const float*)d_in[18];
  p.b_o   = (const float*)d_in[19];
  p.ln_g  = (const float*)d_in[20];
  p.ln_b  = (const float*)d_in[21];
  p.W_a3  = (const float*)d_in[22];
  p.b_a3  = (const float*)d_in[23];
  p.ct    = (const int*)d_in[24];
  p.out   = (float*)d_out;
  p.wsf   = (float*)d_ws;
  p.wsi   = (int*)d_ws;

  hipLaunchKernelGGL(k_init, dim3(NBLK), dim3(256), 0, stream, p);
  hipLaunchKernelGGL(k_scan, dim3(NBLK), dim3(256), 0, stream, p);
}